// Round 17
// baseline (231.807 us; speedup 1.0000x reference)
//
#include <hip/hip_runtime.h>
#include <math.h>

// Problem constants: N=32768 nodes, E=262144 edges, HID=64, HEADS=4
#define HIDDEN 64
#define HEADS 4
#define HC 256   // HEADS * HIDDEN
#define CAP 64   // bucket capacity per dst node (Poisson(8): P(deg>64) ~ 0)

typedef __attribute__((ext_vector_type(8))) short short8;   // 8 bf16 (4 VGPRs)
typedef __attribute__((ext_vector_type(4))) float f32x4;    // MFMA acc

__device__ __forceinline__ unsigned short f2bf(float f) {
    unsigned int u = __float_as_uint(f);
    u += 0x7fffu + ((u >> 16) & 1u);   // round-to-nearest-even
    return (unsigned short)(u >> 16);
}

// ---------------- fused prep + bucket (role-split, no inter-role deps) ------
// [0,1024):     bucket: slot=dst*CAP+cnt; sb[slot]=src, eab[slot]=bf16 ea (8B)
// [1024,3072):  zb = bf16(h), 4 floats/thread
// [3072,3136):  wt1/wt2[c*64+k] = bf16(W[k*256+c])  (transposed, W^T rows)
// 3136:         wr (We @ att_edge reductions, both layers)
// Requires counts==0 on entry (hipMemsetAsync before launch).
__global__ __launch_bounds__(256) void k_fused(const int* __restrict__ dst,
                                               const int* __restrict__ src,
                                               const float* __restrict__ ea,
                                               const float* __restrict__ h,
                                               const float* __restrict__ W1f,
                                               const float* __restrict__ W2f,
                                               const float* __restrict__ We1,
                                               const float* __restrict__ at1,
                                               const float* __restrict__ We2,
                                               const float* __restrict__ at2,
                                               int* __restrict__ counts,
                                               int* __restrict__ sb,
                                               ushort* __restrict__ eab,
                                               ushort* __restrict__ zb,
                                               ushort* __restrict__ wt1,
                                               ushort* __restrict__ wt2,
                                               float* __restrict__ wr, int E) {
    int t = threadIdx.x, b = blockIdx.x;
    if (b < 1024) {
        int e = b * 256 + t;
        if (e < E) {
            int d = dst[e];
            int c = atomicAdd(&counts[d], 1);
            if (c < CAP) {   // statistically impossible overflow; safety clamp
                size_t slot = (size_t)d * CAP + c;
                sb[slot] = src[e];
                ushort4 ev;
                ev.x = f2bf(ea[e * 3 + 0]);
                ev.y = f2bf(ea[e * 3 + 1]);
                ev.z = f2bf(ea[e * 3 + 2]);
                ev.w = 0;
                *(ushort4*)&eab[slot * 4] = ev;
            }
        }
    } else if (b < 3072) {
        int i = (b - 1024) * 256 + t;
        float4 v = ((const float4*)h)[i];
        ushort4 o;
        o.x = f2bf(v.x); o.y = f2bf(v.y); o.z = f2bf(v.z); o.w = f2bf(v.w);
        ((ushort4*)zb)[i] = o;
    } else if (b < 3136) {
        int j = (b - 3072) * 256 + t;   // 0..16383
        int c = j >> 6, k = j & 63;
        wt1[j] = f2bf(W1f[k * HC + c]);
        wt2[j] = f2bf(W2f[k * HC + c]);
    } else {
        int wv = t >> 6, lane = t & 63;
#pragma unroll
        for (int it = 0; it < 6; ++it) {
            int comb = wv + it * 4;          // 0..23
            int layer = comb / 12;
            int dh = comb % 12;
            int d = dh >> 2, hh = dh & 3;
            const float* We = layer ? We2 : We1;
            const float* at = layer ? at2 : at1;
            float v = We[d * HC + hh * HIDDEN + lane] * at[hh * HIDDEN + lane];
            for (int o = 32; o > 0; o >>= 1) v += __shfl_down(v, o);
            if (lane == 0) wr[layer * 16 + d * HEADS + hh] = v;
        }
    }
}

// ---------------- MFMA transform, operand-swapped (R15-proven) ----------------
__global__ __launch_bounds__(256) void k_tmfma(const ushort* __restrict__ zb,
                                               const ushort* __restrict__ wt,
                                               const float* __restrict__ asw,
                                               const float* __restrict__ adw,
                                               ushort* __restrict__ xb,
                                               float* __restrict__ as_,
                                               float* __restrict__ ad_) {
    int wave = threadIdx.x >> 6, lane = threadIdx.x & 63;
    int q = lane & 15, quad = lane >> 4;
    int row0 = blockIdx.x * 64 + wave * 16;

    const ushort* zrow = zb + (size_t)(row0 + q) * 64 + quad * 8;
    short8 bz0 = *(const short8*)(zrow);
    short8 bz1 = *(const short8*)(zrow + 32);

#pragma unroll
    for (int h = 0; h < 4; ++h) {
        float vs = 0.f, vd = 0.f;
#pragma unroll
        for (int nt = 0; nt < 4; ++nt) {
            int col0 = h * 64 + nt * 16;
            const ushort* wrow = wt + (size_t)(col0 + q) * 64 + quad * 8;
            short8 aw0 = *(const short8*)(wrow);
            short8 aw1 = *(const short8*)(wrow + 32);
            f32x4 acc = {0.f, 0.f, 0.f, 0.f};
            acc = __builtin_amdgcn_mfma_f32_16x16x32_bf16(aw0, bz0, acc, 0, 0, 0);
            acc = __builtin_amdgcn_mfma_f32_16x16x32_bf16(aw1, bz1, acc, 0, 0, 0);
            float4 aw4 = *(const float4*)&asw[col0 + quad * 4];
            float4 dw4 = *(const float4*)&adw[col0 + quad * 4];
            ushort4 st;
            st.x = f2bf(acc[0]); st.y = f2bf(acc[1]);
            st.z = f2bf(acc[2]); st.w = f2bf(acc[3]);
            *(ushort4*)&xb[(size_t)(row0 + q) * HC + col0 + quad * 4] = st;
            vs += acc[0] * aw4.x + acc[1] * aw4.y + acc[2] * aw4.z + acc[3] * aw4.w;
            vd += acc[0] * dw4.x + acc[1] * dw4.y + acc[2] * dw4.z + acc[3] * dw4.w;
        }
        vs += __shfl_xor(vs, 16); vs += __shfl_xor(vs, 32);
        vd += __shfl_xor(vd, 16); vd += __shfl_xor(vd, 32);
        if (quad == 0) {
            as_[(row0 + q) * 4 + h] = vs;
            ad_[(row0 + q) * 4 + h] = vd;
        }
    }
}

// Two-node-interleaved aggregate: each wave processes nodes (n0,n1) with
// interleaved stats + gather streams -> 2x memory-level parallelism.
// lane = h*16 + sub; gather (e,g) = (sub&1, sub>>1). Guards are wave-uniform.
__global__ __launch_bounds__(256) void k_aggregate(
        const ushort* __restrict__ xb, const ushort* __restrict__ eab,
        const int* __restrict__ sb, const int* __restrict__ counts,
        const float* __restrict__ as_, const float* __restrict__ ad_,
        const float* __restrict__ wrl,
        const float* __restrict__ bias, const float* __restrict__ lng,
        const float* __restrict__ lnb, float* __restrict__ outf,
        ushort* __restrict__ outb, int N) {
    int lane = threadIdx.x & 63;
    int h = lane >> 4, sub = lane & 15;
    int e = sub & 1, g = sub >> 1;
    int wid = blockIdx.x * 4 + (threadIdx.x >> 6);
    int nwaves = gridDim.x * 4;

    float w0c = wrl[h], w1c = wrl[4 + h], w2c = wrl[8 + h];

    float bs[8], gm[8], bt[8];
#pragma unroll
    for (int k = 0; k < 8; ++k) {
        bs[k] = bias[g * 8 + k];
        gm[k] = lng[g * 8 + k];
        bt[k] = lnb[g * 8 + k];
    }

    for (int np = wid; np * 2 < N; np += nwaves) {
        int n0 = np * 2, n1 = np * 2 + 1;
        int deg0 = counts[n0]; if (deg0 > CAP) deg0 = CAP;
        int deg1 = counts[n1]; if (deg1 > CAP) deg1 = CAP;
        int base0 = n0 * CAP, base1 = n1 * CAP;
        float ad0 = ad_[n0 * 4 + h], ad1 = ad_[n1 * 4 + h];

        float ssum0 = 0.f, ssum1 = 0.f;
        float acc0[8], acc1[8];
#pragma unroll
        for (int k = 0; k < 8; ++k) { acc0[k] = 0.f; acc1[k] = 0.f; }

        int dmax = deg0 > deg1 ? deg0 : deg1;
        for (int cs = 0; cs < dmax; cs += 16) {
            int idx = cs + sub;
            // stats, node 0
            int s0v = 0; float w0v = 0.f;
            if (idx < deg0) {
                s0v = sb[base0 + idx];
                ushort4 ev = *(const ushort4*)&eab[(size_t)(base0 + idx) * 4];
                float a0 = __uint_as_float((unsigned)ev.x << 16);
                float a1 = __uint_as_float((unsigned)ev.y << 16);
                float a2 = __uint_as_float((unsigned)ev.z << 16);
                float lg = as_[s0v * 4 + h] + ad0 + a0 * w0c + a1 * w1c + a2 * w2c;
                lg = (lg >= 0.f) ? lg : 0.2f * lg;
                w0v = __expf(lg);
            }
            // stats, node 1 (independent chain)
            int s1v = 0; float w1v = 0.f;
            if (idx < deg1) {
                s1v = sb[base1 + idx];
                ushort4 ev = *(const ushort4*)&eab[(size_t)(base1 + idx) * 4];
                float a0 = __uint_as_float((unsigned)ev.x << 16);
                float a1 = __uint_as_float((unsigned)ev.y << 16);
                float a2 = __uint_as_float((unsigned)ev.z << 16);
                float lg = as_[s1v * 4 + h] + ad1 + a0 * w0c + a1 * w1c + a2 * w2c;
                lg = (lg >= 0.f) ? lg : 0.2f * lg;
                w1v = __expf(lg);
            }
            ssum0 += w0v;
            ssum1 += w1v;

            int jb0 = deg0 - cs; if (jb0 > 16) jb0 = 16; if (jb0 < 0) jb0 = 0;
            int jb1 = deg1 - cs; if (jb1 > 16) jb1 = 16; if (jb1 < 0) jb1 = 0;
            int jbm = jb0 > jb1 ? jb0 : jb1;
            for (int j4 = 0; j4 < jbm; j4 += 4) {
                if (j4 < jb0) {   // wave-uniform guard
                    int sl0 = h * 16 + j4 + e;
                    int sl1 = h * 16 + j4 + 2 + e;
                    float q0 = __shfl(w0v, sl0);
                    int t0 = __shfl(s0v, sl0);
                    float q1 = __shfl(w0v, sl1);
                    int t1 = __shfl(s0v, sl1);
                    uint4 r0 = *(const uint4*)&xb[(size_t)t0 * HC + h * HIDDEN + g * 8];
                    uint4 r1 = *(const uint4*)&xb[(size_t)t1 * HC + h * HIDDEN + g * 8];
                    unsigned int u0[4] = {r0.x, r0.y, r0.z, r0.w};
                    unsigned int u1[4] = {r1.x, r1.y, r1.z, r1.w};
#pragma unroll
                    for (int k = 0; k < 4; ++k) {
                        acc0[2 * k + 0] += q0 * __uint_as_float(u0[k] << 16);
                        acc0[2 * k + 1] += q0 * __uint_as_float(u0[k] & 0xffff0000u);
                        acc0[2 * k + 0] += q1 * __uint_as_float(u1[k] << 16);
                        acc0[2 * k + 1] += q1 * __uint_as_float(u1[k] & 0xffff0000u);
                    }
                }
                if (j4 < jb1) {
                    int sl0 = h * 16 + j4 + e;
                    int sl1 = h * 16 + j4 + 2 + e;
                    float q0 = __shfl(w1v, sl0);
                    int t0 = __shfl(s1v, sl0);
                    float q1 = __shfl(w1v, sl1);
                    int t1 = __shfl(s1v, sl1);
                    uint4 r0 = *(const uint4*)&xb[(size_t)t0 * HC + h * HIDDEN + g * 8];
                    uint4 r1 = *(const uint4*)&xb[(size_t)t1 * HC + h * HIDDEN + g * 8];
                    unsigned int u0[4] = {r0.x, r0.y, r0.z, r0.w};
                    unsigned int u1[4] = {r1.x, r1.y, r1.z, r1.w};
#pragma unroll
                    for (int k = 0; k < 4; ++k) {
                        acc1[2 * k + 0] += q0 * __uint_as_float(u0[k] << 16);
                        acc1[2 * k + 1] += q0 * __uint_as_float(u0[k] & 0xffff0000u);
                        acc1[2 * k + 0] += q1 * __uint_as_float(u1[k] << 16);
                        acc1[2 * k + 1] += q1 * __uint_as_float(u1[k] & 0xffff0000u);
                    }
                }
            }
        }

        // finalize both nodes
#pragma unroll
        for (int o = 1; o < 16; o <<= 1) {
            ssum0 += __shfl_xor(ssum0, o);
            ssum1 += __shfl_xor(ssum1, o);
        }
        float winv0 = 1.f / (ssum0 + 1e-16f);
        float winv1 = 1.f / (ssum1 + 1e-16f);
#pragma unroll
        for (int k = 0; k < 8; ++k) {
            acc0[k] *= winv0;
            acc1[k] *= winv1;
            acc0[k] += __shfl_xor(acc0[k], 1);
            acc0[k] += __shfl_xor(acc0[k], 16);
            acc0[k] += __shfl_xor(acc0[k], 32);
            acc1[k] += __shfl_xor(acc1[k], 1);
            acc1[k] += __shfl_xor(acc1[k], 16);
            acc1[k] += __shfl_xor(acc1[k], 32);
        }

#pragma unroll
        for (int which = 0; which < 2; ++which) {
            float* accp = which ? acc1 : acc0;
            int n = which ? n1 : n0;
            float u8[8], s1 = 0.f;
#pragma unroll
            for (int k = 0; k < 8; ++k) {
                u8[k] = accp[k] * 0.25f + bs[k];
                s1 += u8[k];
            }
#pragma unroll
            for (int o = 2; o < 16; o <<= 1) s1 += __shfl_xor(s1, o);
            float mu = s1 * (1.f / 64.f);
            float s2 = 0.f;
#pragma unroll
            for (int k = 0; k < 8; ++k) {
                float d = u8[k] - mu;
                s2 += d * d;
            }
#pragma unroll
            for (int o = 2; o < 16; o <<= 1) s2 += __shfl_xor(s2, o);
            float rstd = rsqrtf(s2 * (1.f / 64.f) + 1e-5f);
            float r[8];
#pragma unroll
            for (int k = 0; k < 8; ++k) {
                float y = (u8[k] - mu) * rstd * gm[k] + bt[k];
                r[k] = y / (1.f + __expf(-y));
            }
            if ((lane & 49) == 0) {   // h==0 && e==0: 8 lanes, one per g
                if (outb) {
                    uint4 pk;
                    pk.x = (unsigned)f2bf(r[0]) | ((unsigned)f2bf(r[1]) << 16);
                    pk.y = (unsigned)f2bf(r[2]) | ((unsigned)f2bf(r[3]) << 16);
                    pk.z = (unsigned)f2bf(r[4]) | ((unsigned)f2bf(r[5]) << 16);
                    pk.w = (unsigned)f2bf(r[6]) | ((unsigned)f2bf(r[7]) << 16);
                    *(uint4*)&outb[(size_t)n * HIDDEN + g * 8] = pk;
                } else {
                    float4* o4 = (float4*)&outf[(size_t)n * HIDDEN + g * 8];
                    o4[0] = make_float4(r[0], r[1], r[2], r[3]);
                    o4[1] = make_float4(r[4], r[5], r[6], r[7]);
                }
            }
        }
    }
}

// ---------------- launch ----------------

extern "C" void kernel_launch(void* const* d_in, const int* in_sizes, int n_in,
                              void* d_out, int out_size, void* d_ws, size_t ws_size,
                              hipStream_t stream) {
    const float* h   = (const float*)d_in[1];
    const int*   ei  = (const int*)d_in[2];
    const float* ea  = (const float*)d_in[3];
    const float* W1  = (const float*)d_in[4];
    const float* We1 = (const float*)d_in[5];
    const float* as1 = (const float*)d_in[6];
    const float* ad1 = (const float*)d_in[7];
    const float* ae1 = (const float*)d_in[8];
    const float* b1  = (const float*)d_in[9];
    const float* lg1 = (const float*)d_in[10];
    const float* lb1 = (const float*)d_in[11];
    const float* W2  = (const float*)d_in[12];
    const float* We2 = (const float*)d_in[13];
    const float* as2 = (const float*)d_in[14];
    const float* ad2 = (const float*)d_in[15];
    const float* ae2 = (const float*)d_in[16];
    const float* b2  = (const float*)d_in[17];
    const float* lg2 = (const float*)d_in[18];
    const float* lb2 = (const float*)d_in[19];

    const int N = in_sizes[1] / HIDDEN;   // 32768
    const int E = in_sizes[2] / 2;        // 262144
    const int* srcp = ei;
    const int* dstp = ei + E;

    // workspace layout (all regions fully written before read)
    char* w = (char*)d_ws;
    ushort* xb    = (ushort*)w; w += (size_t)N * HC * 2;        // 16.75 MB
    ushort* zb    = (ushort*)w; w += (size_t)N * HIDDEN * 2;    // 4 MB
    float* as_    = (float*)w;  w += (size_t)N * HEADS * 4;
    float* adv    = (float*)w;  w += (size_t)N * HEADS * 4;
    ushort* wt1   = (ushort*)w; w += 16384 * 2;
    ushort* wt2   = (ushort*)w; w += 16384 * 2;
    float* wr     = (float*)w;  w += 128;
    int* counts   = (int*)w;    w += (size_t)N * 4;
    int* sb       = (int*)w;    w += (size_t)N * CAP * 4;       // 8 MB
    ushort* eab   = (ushort*)w; w += (size_t)N * CAP * 4 * 2;   // 16 MB

    // zero counts (memset node in the graph), then fused prep || bucket
    hipMemsetAsync(counts, 0, (size_t)N * 4, stream);
    k_fused<<<3137, 256, 0, stream>>>(dstp, srcp, ea, h, W1, W2,
                                      We1, ae1, We2, ae2,
                                      counts, sb, eab, zb, wt1, wt2, wr, E);

    // layer 1
    k_tmfma<<<N / 64, 256, 0, stream>>>(zb, wt1, as1, ad1, xb, as_, adv);
    k_aggregate<<<4096, 256, 0, stream>>>(xb, eab, sb, counts, as_, adv, wr,
                                          b1, lg1, lb1, nullptr, zb, N);
    // layer 2 (reads zb written by layer-1 aggregate)
    k_tmfma<<<N / 64, 256, 0, stream>>>(zb, wt2, as2, ad2, xb, as_, adv);
    k_aggregate<<<4096, 256, 0, stream>>>(xb, eab, sb, counts, as_, adv, wr + 16,
                                          b2, lg2, lb2, (float*)d_out, nullptr, N);
}

// Round 18
// 221.269 us; speedup vs baseline: 1.0476x; 1.0476x over previous
//
#include <hip/hip_runtime.h>
#include <math.h>

// Problem constants: N=32768 nodes, E=262144 edges, HID=64, HEADS=4
#define HIDDEN 64
#define HEADS 4
#define HC 256   // HEADS * HIDDEN
#define CAP 64   // bucket capacity per dst node (Poisson(8): P(deg>64) ~ 0)

typedef __attribute__((ext_vector_type(8))) short short8;   // 8 bf16 (4 VGPRs)
typedef __attribute__((ext_vector_type(4))) float f32x4;    // MFMA acc

__device__ __forceinline__ unsigned short f2bf(float f) {
    unsigned int u = __float_as_uint(f);
    u += 0x7fffu + ((u >> 16) & 1u);   // round-to-nearest-even
    return (unsigned short)(u >> 16);
}

// ---------------- fused prep + bucket (role-split, no inter-role deps) ------
// [0,1024):     bucket: slot=dst*CAP+atomic count; sb[slot]=src, eab[slot]=ea
// [1024,3072):  zb = bf16(h), 4 floats/thread
// [3072,3136):  wt1/wt2[c*64+k] = bf16(W[k*256+c])  (transposed for tmfma)
// 3136:         wr (We @ att_edge reductions, both layers)
// Requires counts==0 on entry (hipMemsetAsync before launch).
__global__ __launch_bounds__(256) void k_fused(const int* __restrict__ dst,
                                               const int* __restrict__ src,
                                               const float* __restrict__ ea,
                                               const float* __restrict__ h,
                                               const float* __restrict__ W1f,
                                               const float* __restrict__ W2f,
                                               const float* __restrict__ We1,
                                               const float* __restrict__ at1,
                                               const float* __restrict__ We2,
                                               const float* __restrict__ at2,
                                               int* __restrict__ counts,
                                               int* __restrict__ sb,
                                               float* __restrict__ eab,
                                               ushort* __restrict__ zb,
                                               ushort* __restrict__ wt1,
                                               ushort* __restrict__ wt2,
                                               float* __restrict__ wr, int E) {
    int t = threadIdx.x, b = blockIdx.x;
    if (b < 1024) {
        int e = b * 256 + t;
        if (e < E) {
            int d = dst[e];
            int c = atomicAdd(&counts[d], 1);
            if (c < CAP) {   // statistically impossible overflow; safety clamp
                size_t slot = (size_t)d * CAP + c;
                sb[slot] = src[e];
                *(float4*)&eab[slot * 4] =
                    make_float4(ea[e * 3 + 0], ea[e * 3 + 1], ea[e * 3 + 2], 0.f);
            }
        }
    } else if (b < 3072) {
        int i = (b - 1024) * 256 + t;
        float4 v = ((const float4*)h)[i];
        ushort4 o;
        o.x = f2bf(v.x); o.y = f2bf(v.y); o.z = f2bf(v.z); o.w = f2bf(v.w);
        ((ushort4*)zb)[i] = o;
    } else if (b < 3136) {
        int j = (b - 3072) * 256 + t;   // 0..16383
        int c = j >> 6, k = j & 63;
        wt1[j] = f2bf(W1f[k * HC + c]);
        wt2[j] = f2bf(W2f[k * HC + c]);
    } else {
        int wv = t >> 6, lane = t & 63;
#pragma unroll
        for (int it = 0; it < 6; ++it) {
            int comb = wv + it * 4;          // 0..23
            int layer = comb / 12;
            int dh = comb % 12;
            int d = dh >> 2, hh = dh & 3;
            const float* We = layer ? We2 : We1;
            const float* at = layer ? at2 : at1;
            float v = We[d * HC + hh * HIDDEN + lane] * at[hh * HIDDEN + lane];
            for (int o = 32; o > 0; o >>= 1) v += __shfl_down(v, o);
            if (lane == 0) wr[layer * 16 + d * HEADS + hh] = v;
        }
    }
}

// ---------------- MFMA transform (R12-proven) ----------------
// x = z @ W (64 -> 256) via mfma_f32_16x16x32_bf16, fused alpha_src/alpha_dst.
__global__ __launch_bounds__(256) void k_tmfma(const ushort* __restrict__ zb,
                                               const ushort* __restrict__ wt,
                                               const float* __restrict__ asw,
                                               const float* __restrict__ adw,
                                               ushort* __restrict__ xb,
                                               float* __restrict__ as_,
                                               float* __restrict__ ad_) {
    int wave = threadIdx.x >> 6, lane = threadIdx.x & 63;
    int q = lane & 15, quad = lane >> 4;
    int row0 = blockIdx.x * 64 + wave * 16;

    const ushort* zrow = zb + (size_t)(row0 + q) * 64 + quad * 8;
    short8 a0 = *(const short8*)(zrow);
    short8 a1 = *(const short8*)(zrow + 32);

#pragma unroll
    for (int h = 0; h < 4; ++h) {
        float vs[4] = {0.f, 0.f, 0.f, 0.f};
        float vd[4] = {0.f, 0.f, 0.f, 0.f};
#pragma unroll
        for (int nt = 0; nt < 4; ++nt) {
            int col0 = h * 64 + nt * 16;
            const ushort* wrow = wt + (size_t)(col0 + q) * 64 + quad * 8;
            short8 b0 = *(const short8*)(wrow);
            short8 b1 = *(const short8*)(wrow + 32);
            f32x4 acc = {0.f, 0.f, 0.f, 0.f};
            acc = __builtin_amdgcn_mfma_f32_16x16x32_bf16(a0, b0, acc, 0, 0, 0);
            acc = __builtin_amdgcn_mfma_f32_16x16x32_bf16(a1, b1, acc, 0, 0, 0);
            int c = col0 + q;
            float aw = asw[c], dw = adw[c];
#pragma unroll
            for (int r = 0; r < 4; ++r) {
                float v = acc[r];
                xb[(size_t)(row0 + quad * 4 + r) * HC + c] = f2bf(v);
                vs[r] += v * aw;
                vd[r] += v * dw;
            }
        }
#pragma unroll
        for (int o = 1; o < 16; o <<= 1) {
#pragma unroll
            for (int r = 0; r < 4; ++r) {
                vs[r] += __shfl_xor(vs[r], o);
                vd[r] += __shfl_xor(vd[r], o);
            }
        }
        if (q < 4) {
            int n = row0 + quad * 4 + q;
            as_[n * 4 + h] = vs[q];
            ad_[n * 4 + h] = vd[q];
        }
    }
}

// Single-pass aggregate (R12-proven) with inline aes from raw edge_attr + wr.
// Wave per node, grid-stride. lane = h*16 + sub; gather (e,g)=(sub&1,sub>>1).
__global__ __launch_bounds__(256) void k_aggregate(
        const ushort* __restrict__ xb, const float* __restrict__ eab,
        const int* __restrict__ sb, const int* __restrict__ counts,
        const float* __restrict__ as_, const float* __restrict__ ad_,
        const float* __restrict__ wrl,
        const float* __restrict__ bias, const float* __restrict__ lng,
        const float* __restrict__ lnb, float* __restrict__ outf,
        ushort* __restrict__ outb, int N) {
    int lane = threadIdx.x & 63;
    int h = lane >> 4, sub = lane & 15;
    int e = sub & 1, g = sub >> 1;
    int wid = blockIdx.x * 4 + (threadIdx.x >> 6);
    int nwaves = gridDim.x * 4;

    // per-lane wr row for this head (L2-resident 12 floats/layer)
    float w0 = wrl[h], w1 = wrl[4 + h], w2 = wrl[8 + h];

    float bs[8], gm[8], bt[8];
#pragma unroll
    for (int k = 0; k < 8; ++k) {
        bs[k] = bias[g * 8 + k];
        gm[k] = lng[g * 8 + k];
        bt[k] = lnb[g * 8 + k];
    }

    for (int n = wid; n < N; n += nwaves) {
        int deg = counts[n];
        if (deg > CAP) deg = CAP;
        int base = n * CAP;
        float ad4 = ad_[n * 4 + h];

        float ssum = 0.f;
        float acc[8];
#pragma unroll
        for (int k = 0; k < 8; ++k) acc[k] = 0.f;

        for (int cs = 0; cs < deg; cs += 16) {
            int idx = cs + sub;
            int s_sub = 0;
            float wgt = 0.f;
            if (idx < deg) {
                s_sub = sb[base + idx];
                float4 av = *(const float4*)&eab[(size_t)(base + idx) * 4];
                float lg = as_[s_sub * 4 + h] + ad4
                         + av.x * w0 + av.y * w1 + av.z * w2;
                lg = (lg >= 0.f) ? lg : 0.2f * lg;
                wgt = __expf(lg);
            }
            ssum += wgt;

            int jb = deg - cs; if (jb > 16) jb = 16;
            for (int j4 = 0; j4 < jb; j4 += 4) {
                int sl0 = h * 16 + j4 + e;
                int sl1 = h * 16 + j4 + 2 + e;
                float q0 = __shfl(wgt, sl0);
                int s0 = __shfl(s_sub, sl0);
                float q1 = __shfl(wgt, sl1);
                int s1 = __shfl(s_sub, sl1);
                uint4 r0 = *(const uint4*)&xb[(size_t)s0 * HC + h * HIDDEN + g * 8];
                uint4 r1 = *(const uint4*)&xb[(size_t)s1 * HC + h * HIDDEN + g * 8];
                unsigned int u0[4] = {r0.x, r0.y, r0.z, r0.w};
                unsigned int u1[4] = {r1.x, r1.y, r1.z, r1.w};
#pragma unroll
                for (int k = 0; k < 4; ++k) {
                    acc[2 * k + 0] += q0 * __uint_as_float(u0[k] << 16);
                    acc[2 * k + 1] += q0 * __uint_as_float(u0[k] & 0xffff0000u);
                    acc[2 * k + 0] += q1 * __uint_as_float(u1[k] << 16);
                    acc[2 * k + 1] += q1 * __uint_as_float(u1[k] & 0xffff0000u);
                }
            }
        }
        // reduce ssum over the 16 lanes of this head group (once per node)
#pragma unroll
        for (int o = 1; o < 16; o <<= 1) ssum += __shfl_xor(ssum, o);
        float winv = 1.f / (ssum + 1e-16f);
#pragma unroll
        for (int k = 0; k < 8; ++k) acc[k] *= winv;
        // reduce acc over edge slot (bit 0) and heads (bits 4,5)
#pragma unroll
        for (int k = 0; k < 8; ++k) {
            acc[k] += __shfl_xor(acc[k], 1);
            acc[k] += __shfl_xor(acc[k], 16);
            acc[k] += __shfl_xor(acc[k], 32);
        }

        // epilogue: head mean + bias + LayerNorm + SiLU
        float u8[8], s1 = 0.f;
#pragma unroll
        for (int k = 0; k < 8; ++k) {
            u8[k] = acc[k] * 0.25f + bs[k];
            s1 += u8[k];
        }
#pragma unroll
        for (int o = 2; o < 16; o <<= 1) s1 += __shfl_xor(s1, o);
        float mu = s1 * (1.f / 64.f);
        float s2 = 0.f;
#pragma unroll
        for (int k = 0; k < 8; ++k) {
            float d = u8[k] - mu;
            s2 += d * d;
        }
#pragma unroll
        for (int o = 2; o < 16; o <<= 1) s2 += __shfl_xor(s2, o);
        float rstd = rsqrtf(s2 * (1.f / 64.f) + 1e-5f);
        float r[8];
#pragma unroll
        for (int k = 0; k < 8; ++k) {
            float y = (u8[k] - mu) * rstd * gm[k] + bt[k];
            r[k] = y / (1.f + __expf(-y));
        }
        if ((lane & 49) == 0) {   // h==0 && e==0: 8 lanes, one per g
            if (outb) {
                uint4 pk;
                pk.x = (unsigned)f2bf(r[0]) | ((unsigned)f2bf(r[1]) << 16);
                pk.y = (unsigned)f2bf(r[2]) | ((unsigned)f2bf(r[3]) << 16);
                pk.z = (unsigned)f2bf(r[4]) | ((unsigned)f2bf(r[5]) << 16);
                pk.w = (unsigned)f2bf(r[6]) | ((unsigned)f2bf(r[7]) << 16);
                *(uint4*)&outb[(size_t)n * HIDDEN + g * 8] = pk;
            } else {
                float4* o4 = (float4*)&outf[(size_t)n * HIDDEN + g * 8];
                o4[0] = make_float4(r[0], r[1], r[2], r[3]);
                o4[1] = make_float4(r[4], r[5], r[6], r[7]);
            }
        }
    }
}

// ---------------- launch ----------------

extern "C" void kernel_launch(void* const* d_in, const int* in_sizes, int n_in,
                              void* d_out, int out_size, void* d_ws, size_t ws_size,
                              hipStream_t stream) {
    const float* h   = (const float*)d_in[1];
    const int*   ei  = (const int*)d_in[2];
    const float* ea  = (const float*)d_in[3];
    const float* W1  = (const float*)d_in[4];
    const float* We1 = (const float*)d_in[5];
    const float* as1 = (const float*)d_in[6];
    const float* ad1 = (const float*)d_in[7];
    const float* ae1 = (const float*)d_in[8];
    const float* b1  = (const float*)d_in[9];
    const float* lg1 = (const float*)d_in[10];
    const float* lb1 = (const float*)d_in[11];
    const float* W2  = (const float*)d_in[12];
    const float* We2 = (const float*)d_in[13];
    const float* as2 = (const float*)d_in[14];
    const float* ad2 = (const float*)d_in[15];
    const float* ae2 = (const float*)d_in[16];
    const float* b2  = (const float*)d_in[17];
    const float* lg2 = (const float*)d_in[18];
    const float* lb2 = (const float*)d_in[19];

    const int N = in_sizes[1] / HIDDEN;   // 32768
    const int E = in_sizes[2] / 2;        // 262144
    const int* srcp = ei;
    const int* dstp = ei + E;

    // workspace layout (all regions fully written before read)
    char* w = (char*)d_ws;
    ushort* xb    = (ushort*)w; w += (size_t)N * HC * 2;        // 16.75 MB
    ushort* zb    = (ushort*)w; w += (size_t)N * HIDDEN * 2;    // 4 MB
    float* as_    = (float*)w;  w += (size_t)N * HEADS * 4;
    float* adv    = (float*)w;  w += (size_t)N * HEADS * 4;
    ushort* wt1   = (ushort*)w; w += 16384 * 2;
    ushort* wt2   = (ushort*)w; w += 16384 * 2;
    float* wr     = (float*)w;  w += 128;
    int* counts   = (int*)w;    w += (size_t)N * 4;
    int* sb       = (int*)w;    w += (size_t)N * CAP * 4;       // 8 MB
    float* eab    = (float*)w;  w += (size_t)N * CAP * 4 * 4;   // 32 MB

    // zero counts (memset node in the graph), then fused prep || bucket
    hipMemsetAsync(counts, 0, (size_t)N * 4, stream);
    k_fused<<<3137, 256, 0, stream>>>(dstp, srcp, ea, h, W1, W2,
                                      We1, ae1, We2, ae2,
                                      counts, sb, eab, zb, wt1, wt2, wr, E);

    // layer 1
    k_tmfma<<<N / 64, 256, 0, stream>>>(zb, wt1, as1, ad1, xb, as_, adv);
    k_aggregate<<<4096, 256, 0, stream>>>(xb, eab, sb, counts, as_, adv, wr,
                                          b1, lg1, lb1, nullptr, zb, N);
    // layer 2 (reads zb written by layer-1 aggregate)
    k_tmfma<<<N / 64, 256, 0, stream>>>(zb, wt2, as2, ad2, xb, as_, adv);
    k_aggregate<<<4096, 256, 0, stream>>>(xb, eab, sb, counts, as_, adv, wr + 16,
                                          b2, lg2, lb2, (float*)d_out, nullptr, N);
}